// Round 1
// baseline (344.544 us; speedup 1.0000x reference)
//
#include <hip/hip_runtime.h>
#include <hip/hip_bf16.h>

typedef __attribute__((ext_vector_type(8))) short short8;
typedef __attribute__((ext_vector_type(4))) short s16x4;
typedef __attribute__((ext_vector_type(4))) float f32x4;
typedef __attribute__((ext_vector_type(2))) _Float16 h2;

typedef const __attribute__((address_space(1))) unsigned* gp1;
typedef __attribute__((address_space(3))) unsigned* lp3;

__device__ inline short f2bf(float f) {
    union { float f; unsigned u; } v; v.f = f;
    unsigned r = v.u + 0x7fffu + ((v.u >> 16) & 1u);
    return (short)(r >> 16);
}

// ---------------------------------------------------------------------------
// P0: fp32 -> bf16 flat convert (x)
// ---------------------------------------------------------------------------
__global__ __launch_bounds__(256) void cvt_bf16(
    const float* __restrict__ src, short* __restrict__ dst, int n4)
{
    int i = blockIdx.x * 256 + threadIdx.x;
    if (i < n4) {
        float4 v = ((const float4*)src)[i];
        s16x4 o = { f2bf(v.x), f2bf(v.y), f2bf(v.z), f2bf(v.w) };
        ((s16x4*)dst)[i] = o;
    }
}

// ---------------------------------------------------------------------------
// P1: W[K][N] fp32 -> W^T[N][K] bf16 (64x64 LDS tile transpose)
// ---------------------------------------------------------------------------
__global__ __launch_bounds__(256) void tr_w(
    const float* __restrict__ src, short* __restrict__ dst, int K, int N)
{
    __shared__ float t[64][65];
    const int k0 = blockIdx.x * 64, n0 = blockIdx.y * 64;
    const int r = threadIdx.x >> 4, c4 = (threadIdx.x & 15) * 4;
#pragma unroll
    for (int j = 0; j < 4; j++) {
        float4 v = *(const float4*)(src + (size_t)(k0 + r + 16 * j) * N + n0 + c4);
        t[r + 16 * j][c4 + 0] = v.x; t[r + 16 * j][c4 + 1] = v.y;
        t[r + 16 * j][c4 + 2] = v.z; t[r + 16 * j][c4 + 3] = v.w;
    }
    __syncthreads();
#pragma unroll
    for (int j = 0; j < 4; j++) {
        const int n = r + 16 * j;
        s16x4 o = { f2bf(t[c4 + 0][n]), f2bf(t[c4 + 1][n]),
                    f2bf(t[c4 + 2][n]), f2bf(t[c4 + 3][n]) };
        *(s16x4*)(dst + (size_t)(n0 + n) * K + k0 + c4) = o;
    }
}

// ---------------------------------------------------------------------------
// K1: qkv = xb @ WqT^T  (M=8192, K=512, N=1536), m97-style 128x128 tile,
//     BK=32, global_load_lds 16B staging, scatter epilogue to q/k/vT.
// ---------------------------------------------------------------------------
__global__ __launch_bounds__(256) void qkv_gemm(
    const short* __restrict__ A, const short* __restrict__ BT,
    short* __restrict__ q, short* __restrict__ k, short* __restrict__ vt)
{
    __shared__ short sA[128][32];   // NO padding: global_load_lds needs dense
    __shared__ short sB[128][32];

    const int tid  = threadIdx.x;
    const int wv   = tid >> 6, lane = tid & 63;
    const int quad = lane >> 4, l16 = lane & 15;
    const int wr = wv >> 1, wc = wv & 1;
    const int m0 = blockIdx.x * 128, n0 = blockIdx.y * 128;

    f32x4 acc[4][4];
#pragma unroll
    for (int i = 0; i < 4; i++)
#pragma unroll
        for (int j = 0; j < 4; j++) acc[i][j] = (f32x4){0.f, 0.f, 0.f, 0.f};

    // staging: wave wv covers rows wv*32 + j*16 + (lane>>2), col chunk (lane&3)*8
    const short* a_src = A  + (size_t)(m0 + wv * 32 + (lane >> 2)) * 512 + (lane & 3) * 8;
    const short* b_src = BT + (size_t)(n0 + wv * 32 + (lane >> 2)) * 512 + (lane & 3) * 8;
    char* a_dst = (char*)sA + wv * 2048;
    char* b_dst = (char*)sB + wv * 2048;

    for (int ks = 0; ks < 16; ks++) {
        __syncthreads();
        const short* ap = a_src + ks * 32;
        const short* bp = b_src + ks * 32;
        __builtin_amdgcn_global_load_lds((gp1)(ap),            (lp3)(a_dst),        16, 0, 0);
        __builtin_amdgcn_global_load_lds((gp1)(ap + 16 * 512), (lp3)(a_dst + 1024), 16, 0, 0);
        __builtin_amdgcn_global_load_lds((gp1)(bp),            (lp3)(b_dst),        16, 0, 0);
        __builtin_amdgcn_global_load_lds((gp1)(bp + 16 * 512), (lp3)(b_dst + 1024), 16, 0, 0);
        __syncthreads();

        short8 af[4], bf[4];
#pragma unroll
        for (int f = 0; f < 4; f++) {
            af[f] = *(const short8*)&sA[wr * 64 + f * 16 + l16][quad * 8];
            bf[f] = *(const short8*)&sB[wc * 64 + f * 16 + l16][quad * 8];
        }
#pragma unroll
        for (int fm = 0; fm < 4; fm++)
#pragma unroll
            for (int fn = 0; fn < 4; fn++)
                acc[fm][fn] = __builtin_amdgcn_mfma_f32_16x16x32_bf16(
                    af[fm], bf[fn], acc[fm][fn], 0, 0, 0);
    }

    // epilogue: section is uniform per block (n0 multiple of 128, sections 512-aligned)
    const int sec = n0 >> 9;   // 0=q 1=k 2=v
#pragma unroll
    for (int fn = 0; fn < 4; fn++) {
        const int gc = n0 + wc * 64 + fn * 16 + l16;
        const int cc = gc & 511;
        const int h = cc >> 6, d = cc & 63;
#pragma unroll
        for (int fm = 0; fm < 4; fm++)
#pragma unroll
            for (int i = 0; i < 4; i++) {
                const int gm = m0 + wr * 64 + fm * 16 + quad * 4 + i;
                const int b = gm >> 10, n = gm & 1023;
                const int bh = b * 8 + h;
                if (sec == 0)      q[((size_t)(bh * 1024 + n)) * 64 + d] = f2bf(acc[fm][fn][i] * 0.125f);
                else if (sec == 1) k[((size_t)(bh * 1024 + n)) * 64 + d] = f2bf(acc[fm][fn][i]);
                else               vt[((size_t)(bh * 64 + d)) * 1024 + n] = f2bf(acc[fm][fn][i]);
            }
    }
}

// ---------------------------------------------------------------------------
// K2: attention, SWAPPED-QK variant. One block = one (b,h) x 16 query rows.
//     mfma(K,Q) => lane (quad,l16) holds S[q=l16][key=wv*256+t*16+quad*4+i]:
//     row reductions are lane-local + 2 shfls; spd loads are float4;
//     sP halved (split PV over two key-halves) for occupancy.
// ---------------------------------------------------------------------------
__global__ __launch_bounds__(256, 4) void attn_k(
    const short* __restrict__ q, const short* __restrict__ kk,
    const short* __restrict__ vt, const float* __restrict__ spd,
    const float* __restrict__ hm, short* __restrict__ o)
{
    __shared__ short sP[16][520];       // one key-half (512) + 8 pad
    __shared__ float sred[4][4][16];

    const int tid  = threadIdx.x;
    const int wv   = tid >> 6, lane = tid & 63;
    const int quad = lane >> 4, l16 = lane & 15;
    const int qt = blockIdx.x, bh = blockIdx.y;
    const int b = bh >> 3, h = bh & 7;
    const int q0 = qt * 16;

    // Q as B-operand: lane holds q-col=l16, d-rows quad*8.. (same loads as before)
    const short* qb = q + ((size_t)bh * 1024 + q0 + l16) * 64;
    short8 aq0 = *(const short8*)(qb + quad * 8);
    short8 aq1 = *(const short8*)(qb + 32 + quad * 8);

    f32x4 acc[16];
#pragma unroll
    for (int t = 0; t < 16; t++) acc[t] = (f32x4){0.f, 0.f, 0.f, 0.f};

    const short* kbh = kk + (size_t)bh * 1024 * 64;
    // spd row = this lane's q-row; cols = this lane's keys (4 consecutive per tile)
    const float* spdl = spd + ((size_t)b * 1024 + q0 + l16) * 1024 + wv * 256 + quad * 4;

    h2 svp[16][2];
    {
        float4 svf[8];
#pragma unroll
        for (int t = 0; t < 8; t++) svf[t] = *(const float4*)(spdl + t * 16);
#pragma unroll
        for (int t = 0; t < 8; t++) {
            const short* kb = kbh + (size_t)(wv * 256 + t * 16 + l16) * 64;
            short8 b0 = *(const short8*)(kb + quad * 8);
            short8 b1 = *(const short8*)(kb + 32 + quad * 8);
            acc[t] = __builtin_amdgcn_mfma_f32_16x16x32_bf16(b0, aq0, acc[t], 0, 0, 0);
            acc[t] = __builtin_amdgcn_mfma_f32_16x16x32_bf16(b1, aq1, acc[t], 0, 0, 0);
        }
#pragma unroll
        for (int t = 0; t < 8; t++) {
            svp[t][0] = (h2){(_Float16)svf[t].x, (_Float16)svf[t].y};
            svp[t][1] = (h2){(_Float16)svf[t].z, (_Float16)svf[t].w};
        }
#pragma unroll
        for (int t = 0; t < 8; t++) svf[t] = *(const float4*)(spdl + (t + 8) * 16);
#pragma unroll
        for (int t = 8; t < 16; t++) {
            const short* kb = kbh + (size_t)(wv * 256 + t * 16 + l16) * 64;
            short8 b0 = *(const short8*)(kb + quad * 8);
            short8 b1 = *(const short8*)(kb + 32 + quad * 8);
            acc[t] = __builtin_amdgcn_mfma_f32_16x16x32_bf16(b0, aq0, acc[t], 0, 0, 0);
            acc[t] = __builtin_amdgcn_mfma_f32_16x16x32_bf16(b1, aq1, acc[t], 0, 0, 0);
        }
#pragma unroll
        for (int t = 0; t < 8; t++) {
            svp[t + 8][0] = (h2){(_Float16)svf[t].x, (_Float16)svf[t].y};
            svp[t + 8][1] = (h2){(_Float16)svf[t].z, (_Float16)svf[t].w};
        }
    }

    // phase 1: row norms (lane-local over 64 keys, 2 shfls, cross-wave LDS)
    float dn = 0.f, pn = 0.f;
#pragma unroll
    for (int t = 0; t < 16; t++)
#pragma unroll
        for (int i = 0; i < 4; i++) {
            float s  = acc[t][i];
            float sv = (float)svp[t][i >> 1][i & 1];
            float ps = s * sv;
            dn = fmaf(s, s, dn);
            pn = fmaf(ps, ps, pn);
        }
    dn += __shfl_xor(dn, 16, 64); dn += __shfl_xor(dn, 32, 64);
    pn += __shfl_xor(pn, 16, 64); pn += __shfl_xor(pn, 32, 64);
    if (quad == 0) { sred[0][wv][l16] = dn; sred[1][wv][l16] = pn; }
    __syncthreads();
    float dtot = sred[0][0][l16] + sred[0][1][l16] + sred[0][2][l16] + sred[0][3][l16];
    float ptot = sred[1][0][l16] + sred[1][1][l16] + sred[1][2][l16] + sred[1][3][l16];
    const float ratio = sqrtf(dtot) / fmaxf(sqrtf(ptot), 1e-12f);

    // phase 2: bias + max
    float mx = -1e30f;
#pragma unroll
    for (int t = 0; t < 16; t++)
#pragma unroll
        for (int i = 0; i < 4; i++) {
            float s  = acc[t][i];
            float sv = (float)svp[t][i >> 1][i & 1];
            float l  = s * fmaf(sv, ratio, 1.0f);
            acc[t][i] = l;
            mx = fmaxf(mx, l);
        }
    mx = fmaxf(mx, __shfl_xor(mx, 16, 64));
    mx = fmaxf(mx, __shfl_xor(mx, 32, 64));
    if (quad == 0) sred[2][wv][l16] = mx;
    __syncthreads();
    const float mrow = fmaxf(fmaxf(sred[2][0][l16], sred[2][1][l16]),
                             fmaxf(sred[2][2][l16], sred[2][3][l16]));

    // phase 3: exp + sum
    float rs = 0.f;
#pragma unroll
    for (int t = 0; t < 16; t++)
#pragma unroll
        for (int i = 0; i < 4; i++) {
            float p = __expf(acc[t][i] - mrow);
            acc[t][i] = p;
            rs += p;
        }
    rs += __shfl_xor(rs, 16, 64); rs += __shfl_xor(rs, 32, 64);
    if (quad == 0) sred[3][wv][l16] = rs;
    __syncthreads();
    const float hsum = hm[0] + hm[1] + hm[2] + hm[3] + hm[4] + hm[5] + hm[6] + hm[7];
    const float hscale = hm[h] * 8.0f / hsum;
    const float rsum = sred[3][0][l16] + sred[3][1][l16] + sred[3][2][l16] + sred[3][3][l16];
    const float rinv = hscale / rsum;

    // pack P to bf16 (frees acc)
    s16x4 pk[16];
#pragma unroll
    for (int t = 0; t < 16; t++)
        pk[t] = (s16x4){ f2bf(acc[t][0] * rinv), f2bf(acc[t][1] * rinv),
                         f2bf(acc[t][2] * rinv), f2bf(acc[t][3] * rinv) };

    // split PV: half 0 = keys [0,512) (waves 0,1), half 1 = keys [512,1024)
    const short* vb = vt + ((size_t)bh * 64 + wv * 16 + l16) * 1024;
    const int c0 = (wv & 1) * 256 + quad * 4;
    f32x4 oacc = (f32x4){0.f, 0.f, 0.f, 0.f};

    if (wv < 2) {
#pragma unroll
        for (int t = 0; t < 16; t++)
            *(s16x4*)&sP[l16][c0 + t * 16] = pk[t];
    }
    __syncthreads();
#pragma unroll
    for (int kk2 = 0; kk2 < 16; kk2++) {
        short8 pa = *(const short8*)&sP[l16][kk2 * 32 + quad * 8];
        short8 vf = *(const short8*)(vb + kk2 * 32 + quad * 8);
        oacc = __builtin_amdgcn_mfma_f32_16x16x32_bf16(pa, vf, oacc, 0, 0, 0);
    }
    __syncthreads();
    if (wv >= 2) {
#pragma unroll
        for (int t = 0; t < 16; t++)
            *(s16x4*)&sP[l16][c0 + t * 16] = pk[t];
    }
    __syncthreads();
#pragma unroll
    for (int kk2 = 0; kk2 < 16; kk2++) {
        short8 pa = *(const short8*)&sP[l16][kk2 * 32 + quad * 8];
        short8 vf = *(const short8*)(vb + 512 + kk2 * 32 + quad * 8);
        oacc = __builtin_amdgcn_mfma_f32_16x16x32_bf16(pa, vf, oacc, 0, 0, 0);
    }

#pragma unroll
    for (int i = 0; i < 4; i++)
        o[((size_t)(b * 1024 + q0 + quad * 4 + i)) * 512 + h * 64 + wv * 16 + l16]
            = f2bf(oacc[i]);
}

// ---------------------------------------------------------------------------
// K3: out = O @ WoT^T + b_out  (M=8192, K=512, N=512), 128x128 tile, fp32 out
// ---------------------------------------------------------------------------
__global__ __launch_bounds__(256) void out_gemm(
    const short* __restrict__ A, const short* __restrict__ BT,
    const float* __restrict__ bias, float* __restrict__ out)
{
    __shared__ short sA[128][32];
    __shared__ short sB[128][32];

    const int tid  = threadIdx.x;
    const int wv   = tid >> 6, lane = tid & 63;
    const int quad = lane >> 4, l16 = lane & 15;
    const int wr = wv >> 1, wc = wv & 1;
    const int m0 = blockIdx.x * 128, n0 = blockIdx.y * 128;

    f32x4 acc[4][4];
#pragma unroll
    for (int i = 0; i < 4; i++)
#pragma unroll
        for (int j = 0; j < 4; j++) acc[i][j] = (f32x4){0.f, 0.f, 0.f, 0.f};

    const short* a_src = A  + (size_t)(m0 + wv * 32 + (lane >> 2)) * 512 + (lane & 3) * 8;
    const short* b_src = BT + (size_t)(n0 + wv * 32 + (lane >> 2)) * 512 + (lane & 3) * 8;
    char* a_dst = (char*)sA + wv * 2048;
    char* b_dst = (char*)sB + wv * 2048;

    for (int ks = 0; ks < 16; ks++) {
        __syncthreads();
        const short* ap = a_src + ks * 32;
        const short* bp = b_src + ks * 32;
        __builtin_amdgcn_global_load_lds((gp1)(ap),            (lp3)(a_dst),        16, 0, 0);
        __builtin_amdgcn_global_load_lds((gp1)(ap + 16 * 512), (lp3)(a_dst + 1024), 16, 0, 0);
        __builtin_amdgcn_global_load_lds((gp1)(bp),            (lp3)(b_dst),        16, 0, 0);
        __builtin_amdgcn_global_load_lds((gp1)(bp + 16 * 512), (lp3)(b_dst + 1024), 16, 0, 0);
        __syncthreads();

        short8 af[4], bf[4];
#pragma unroll
        for (int f = 0; f < 4; f++) {
            af[f] = *(const short8*)&sA[wr * 64 + f * 16 + l16][quad * 8];
            bf[f] = *(const short8*)&sB[wc * 64 + f * 16 + l16][quad * 8];
        }
#pragma unroll
        for (int fm = 0; fm < 4; fm++)
#pragma unroll
            for (int fn = 0; fn < 4; fn++)
                acc[fm][fn] = __builtin_amdgcn_mfma_f32_16x16x32_bf16(
                    af[fm], bf[fn], acc[fm][fn], 0, 0, 0);
    }

#pragma unroll
    for (int fn = 0; fn < 4; fn++) {
        const int gc = n0 + wc * 64 + fn * 16 + l16;
        const float bv = bias[gc];
#pragma unroll
        for (int fm = 0; fm < 4; fm++)
#pragma unroll
            for (int i = 0; i < 4; i++) {
                const int gm = m0 + wr * 64 + fm * 16 + quad * 4 + i;
                out[(size_t)gm * 512 + gc] = acc[fm][fn][i] + bv;
            }
    }
}

// ---------------------------------------------------------------------------
extern "C" void kernel_launch(void* const* d_in, const int* in_sizes, int n_in,
                              void* d_out, int out_size, void* d_ws, size_t ws_size,
                              hipStream_t stream) {
    const float* x    = (const float*)d_in[0];
    const float* spd  = (const float*)d_in[1];
    const float* hm   = (const float*)d_in[2];
    const float* Wqkv = (const float*)d_in[3];
    const float* Wout = (const float*)d_in[4];
    const float* bout = (const float*)d_in[5];
    float* out = (float*)d_out;

    char* ws = (char*)d_ws;
    short* qw  = (short*)(ws);                      // 8 MB  [bh][n][d] bf16 (pre-scaled)
    short* kw  = (short*)(ws + ((size_t)8  << 20)); // 8 MB  [bh][n][d] bf16
    short* vtw = (short*)(ws + ((size_t)16 << 20)); // 8 MB  [bh][d][n] bf16
    short* ow  = (short*)(ws + ((size_t)24 << 20)); // 8 MB  [b][n][h*64+d] bf16
    short* xb  = (short*)(ws + ((size_t)32 << 20)); // 8 MB  x bf16 [8192][512]
    short* wqT = (short*)(ws + ((size_t)40 << 20)); // 1.5MB Wqkv^T bf16 [1536][512]
    short* woT = (short*)(ws + ((size_t)42 << 20)); // 0.5MB Wout^T bf16 [512][512]

    cvt_bf16<<<4096, 256, 0, stream>>>(x, xb, 8192 * 512 / 4);
    tr_w    <<<dim3(8, 24), 256, 0, stream>>>(Wqkv, wqT, 512, 1536);
    tr_w    <<<dim3(8, 8),  256, 0, stream>>>(Wout, woT, 512, 512);

    qkv_gemm<<<dim3(64, 12), 256, 0, stream>>>(xb, wqT, qw, kw, vtw);
    attn_k  <<<dim3(64, 64), 256, 0, stream>>>(qw, kw, vtw, spd, hm, ow);
    out_gemm<<<dim3(64, 4),  256, 0, stream>>>(ow, woT, bout, out);
}

// Round 2
// 290.343 us; speedup vs baseline: 1.1867x; 1.1867x over previous
//
#include <hip/hip_runtime.h>
#include <hip/hip_bf16.h>

typedef __attribute__((ext_vector_type(8))) short short8;
typedef __attribute__((ext_vector_type(4))) short s16x4;
typedef __attribute__((ext_vector_type(4))) float f32x4;
typedef __attribute__((ext_vector_type(2))) _Float16 h2;

typedef const __attribute__((address_space(1))) unsigned* gp1;
typedef __attribute__((address_space(3))) unsigned* lp3;

__device__ inline short f2bf(float f) {
    union { float f; unsigned u; } v; v.f = f;
    unsigned r = v.u + 0x7fffu + ((v.u >> 16) & 1u);
    return (short)(r >> 16);
}

// ---------------------------------------------------------------------------
// P0: fp32 -> bf16 flat convert (x)
// ---------------------------------------------------------------------------
__global__ __launch_bounds__(256) void cvt_bf16(
    const float* __restrict__ src, short* __restrict__ dst, int n4)
{
    int i = blockIdx.x * 256 + threadIdx.x;
    if (i < n4) {
        float4 v = ((const float4*)src)[i];
        s16x4 o = { f2bf(v.x), f2bf(v.y), f2bf(v.z), f2bf(v.w) };
        ((s16x4*)dst)[i] = o;
    }
}

// ---------------------------------------------------------------------------
// P1: W[K][N] fp32 -> W^T[N][K] bf16 (64x64 LDS tile transpose)
// ---------------------------------------------------------------------------
__global__ __launch_bounds__(256) void tr_w(
    const float* __restrict__ src, short* __restrict__ dst, int K, int N)
{
    __shared__ float t[64][65];
    const int k0 = blockIdx.x * 64, n0 = blockIdx.y * 64;
    const int r = threadIdx.x >> 4, c4 = (threadIdx.x & 15) * 4;
#pragma unroll
    for (int j = 0; j < 4; j++) {
        float4 v = *(const float4*)(src + (size_t)(k0 + r + 16 * j) * N + n0 + c4);
        t[r + 16 * j][c4 + 0] = v.x; t[r + 16 * j][c4 + 1] = v.y;
        t[r + 16 * j][c4 + 2] = v.z; t[r + 16 * j][c4 + 3] = v.w;
    }
    __syncthreads();
#pragma unroll
    for (int j = 0; j < 4; j++) {
        const int n = r + 16 * j;
        s16x4 o = { f2bf(t[c4 + 0][n]), f2bf(t[c4 + 1][n]),
                    f2bf(t[c4 + 2][n]), f2bf(t[c4 + 3][n]) };
        *(s16x4*)(dst + (size_t)(n0 + n) * K + k0 + c4) = o;
    }
}

// ---------------------------------------------------------------------------
// K1: qkv = xb @ WqT^T  (M=8192, K=512, N=1536), m97-style 128x128 tile,
//     BK=32, global_load_lds 16B staging, scatter epilogue to q/k/vT.
// ---------------------------------------------------------------------------
__global__ __launch_bounds__(256) void qkv_gemm(
    const short* __restrict__ A, const short* __restrict__ BT,
    short* __restrict__ q, short* __restrict__ k, short* __restrict__ vt)
{
    __shared__ short sA[128][32];   // NO padding: global_load_lds needs dense
    __shared__ short sB[128][32];

    const int tid  = threadIdx.x;
    const int wv   = tid >> 6, lane = tid & 63;
    const int quad = lane >> 4, l16 = lane & 15;
    const int wr = wv >> 1, wc = wv & 1;
    const int m0 = blockIdx.x * 128, n0 = blockIdx.y * 128;

    f32x4 acc[4][4];
#pragma unroll
    for (int i = 0; i < 4; i++)
#pragma unroll
        for (int j = 0; j < 4; j++) acc[i][j] = (f32x4){0.f, 0.f, 0.f, 0.f};

    // staging: wave wv covers rows wv*32 + j*16 + (lane>>2), col chunk (lane&3)*8
    const short* a_src = A  + (size_t)(m0 + wv * 32 + (lane >> 2)) * 512 + (lane & 3) * 8;
    const short* b_src = BT + (size_t)(n0 + wv * 32 + (lane >> 2)) * 512 + (lane & 3) * 8;
    char* a_dst = (char*)sA + wv * 2048;
    char* b_dst = (char*)sB + wv * 2048;

    for (int ks = 0; ks < 16; ks++) {
        __syncthreads();
        const short* ap = a_src + ks * 32;
        const short* bp = b_src + ks * 32;
        __builtin_amdgcn_global_load_lds((gp1)(ap),            (lp3)(a_dst),        16, 0, 0);
        __builtin_amdgcn_global_load_lds((gp1)(ap + 16 * 512), (lp3)(a_dst + 1024), 16, 0, 0);
        __builtin_amdgcn_global_load_lds((gp1)(bp),            (lp3)(b_dst),        16, 0, 0);
        __builtin_amdgcn_global_load_lds((gp1)(bp + 16 * 512), (lp3)(b_dst + 1024), 16, 0, 0);
        __syncthreads();

        short8 af[4], bf[4];
#pragma unroll
        for (int f = 0; f < 4; f++) {
            af[f] = *(const short8*)&sA[wr * 64 + f * 16 + l16][quad * 8];
            bf[f] = *(const short8*)&sB[wc * 64 + f * 16 + l16][quad * 8];
        }
#pragma unroll
        for (int fm = 0; fm < 4; fm++)
#pragma unroll
            for (int fn = 0; fn < 4; fn++)
                acc[fm][fn] = __builtin_amdgcn_mfma_f32_16x16x32_bf16(
                    af[fm], bf[fn], acc[fm][fn], 0, 0, 0);
    }

    // epilogue: section is uniform per block (n0 multiple of 128, sections 512-aligned)
    const int sec = n0 >> 9;   // 0=q 1=k 2=v
#pragma unroll
    for (int fn = 0; fn < 4; fn++) {
        const int gc = n0 + wc * 64 + fn * 16 + l16;
        const int cc = gc & 511;
        const int h = cc >> 6, d = cc & 63;
#pragma unroll
        for (int fm = 0; fm < 4; fm++)
#pragma unroll
            for (int i = 0; i < 4; i++) {
                const int gm = m0 + wr * 64 + fm * 16 + quad * 4 + i;
                const int b = gm >> 10, n = gm & 1023;
                const int bh = b * 8 + h;
                if (sec == 0)      q[((size_t)(bh * 1024 + n)) * 64 + d] = f2bf(acc[fm][fn][i] * 0.125f);
                else if (sec == 1) k[((size_t)(bh * 1024 + n)) * 64 + d] = f2bf(acc[fm][fn][i]);
                else               vt[((size_t)(bh * 64 + d)) * 1024 + n] = f2bf(acc[fm][fn][i]);
            }
    }
}

// ---------------------------------------------------------------------------
// K2: attention, SWAPPED-QK variant. One block = one (b,h) x 16 query rows.
//     mfma(K,Q) => lane (quad,l16) holds S[q=l16][key=wv*256+t*16+quad*4+i]:
//     row reductions are lane-local + 2 shfls; spd loads are float4;
//     sP halved (split PV over two key-halves) for occupancy.
//     NOTE: launch_bounds min-waves MUST stay at 3 — (256,4) caps VGPR at 64
//     and spills ~120 B/thread to scratch (R1: WRITE_SIZE 8->127 MB, +64 us).
// ---------------------------------------------------------------------------
__global__ __launch_bounds__(256, 3) void attn_k(
    const short* __restrict__ q, const short* __restrict__ kk,
    const short* __restrict__ vt, const float* __restrict__ spd,
    const float* __restrict__ hm, short* __restrict__ o)
{
    __shared__ short sP[16][520];       // one key-half (512) + 8 pad
    __shared__ float sred[4][4][16];

    const int tid  = threadIdx.x;
    const int wv   = tid >> 6, lane = tid & 63;
    const int quad = lane >> 4, l16 = lane & 15;
    const int qt = blockIdx.x, bh = blockIdx.y;
    const int b = bh >> 3, h = bh & 7;
    const int q0 = qt * 16;

    // Q as B-operand: lane holds q-col=l16, d-rows quad*8.. (same loads as before)
    const short* qb = q + ((size_t)bh * 1024 + q0 + l16) * 64;
    short8 aq0 = *(const short8*)(qb + quad * 8);
    short8 aq1 = *(const short8*)(qb + 32 + quad * 8);

    f32x4 acc[16];
#pragma unroll
    for (int t = 0; t < 16; t++) acc[t] = (f32x4){0.f, 0.f, 0.f, 0.f};

    const short* kbh = kk + (size_t)bh * 1024 * 64;
    // spd row = this lane's q-row; cols = this lane's keys (4 consecutive per tile)
    const float* spdl = spd + ((size_t)b * 1024 + q0 + l16) * 1024 + wv * 256 + quad * 4;

    h2 svp[16][2];
    {
        float4 svf[8];
#pragma unroll
        for (int t = 0; t < 8; t++) svf[t] = *(const float4*)(spdl + t * 16);
#pragma unroll
        for (int t = 0; t < 8; t++) {
            const short* kb = kbh + (size_t)(wv * 256 + t * 16 + l16) * 64;
            short8 b0 = *(const short8*)(kb + quad * 8);
            short8 b1 = *(const short8*)(kb + 32 + quad * 8);
            acc[t] = __builtin_amdgcn_mfma_f32_16x16x32_bf16(b0, aq0, acc[t], 0, 0, 0);
            acc[t] = __builtin_amdgcn_mfma_f32_16x16x32_bf16(b1, aq1, acc[t], 0, 0, 0);
        }
#pragma unroll
        for (int t = 0; t < 8; t++) {
            svp[t][0] = (h2){(_Float16)svf[t].x, (_Float16)svf[t].y};
            svp[t][1] = (h2){(_Float16)svf[t].z, (_Float16)svf[t].w};
        }
#pragma unroll
        for (int t = 0; t < 8; t++) svf[t] = *(const float4*)(spdl + (t + 8) * 16);
#pragma unroll
        for (int t = 8; t < 16; t++) {
            const short* kb = kbh + (size_t)(wv * 256 + t * 16 + l16) * 64;
            short8 b0 = *(const short8*)(kb + quad * 8);
            short8 b1 = *(const short8*)(kb + 32 + quad * 8);
            acc[t] = __builtin_amdgcn_mfma_f32_16x16x32_bf16(b0, aq0, acc[t], 0, 0, 0);
            acc[t] = __builtin_amdgcn_mfma_f32_16x16x32_bf16(b1, aq1, acc[t], 0, 0, 0);
        }
#pragma unroll
        for (int t = 0; t < 8; t++) {
            svp[t + 8][0] = (h2){(_Float16)svf[t].x, (_Float16)svf[t].y};
            svp[t + 8][1] = (h2){(_Float16)svf[t].z, (_Float16)svf[t].w};
        }
    }

    // phase 1: row norms (lane-local over 64 keys, 2 shfls, cross-wave LDS)
    float dn = 0.f, pn = 0.f;
#pragma unroll
    for (int t = 0; t < 16; t++)
#pragma unroll
        for (int i = 0; i < 4; i++) {
            float s  = acc[t][i];
            float sv = (float)svp[t][i >> 1][i & 1];
            float ps = s * sv;
            dn = fmaf(s, s, dn);
            pn = fmaf(ps, ps, pn);
        }
    dn += __shfl_xor(dn, 16, 64); dn += __shfl_xor(dn, 32, 64);
    pn += __shfl_xor(pn, 16, 64); pn += __shfl_xor(pn, 32, 64);
    if (quad == 0) { sred[0][wv][l16] = dn; sred[1][wv][l16] = pn; }
    __syncthreads();
    float dtot = sred[0][0][l16] + sred[0][1][l16] + sred[0][2][l16] + sred[0][3][l16];
    float ptot = sred[1][0][l16] + sred[1][1][l16] + sred[1][2][l16] + sred[1][3][l16];
    const float ratio = sqrtf(dtot) / fmaxf(sqrtf(ptot), 1e-12f);

    // phase 2: bias + max
    float mx = -1e30f;
#pragma unroll
    for (int t = 0; t < 16; t++)
#pragma unroll
        for (int i = 0; i < 4; i++) {
            float s  = acc[t][i];
            float sv = (float)svp[t][i >> 1][i & 1];
            float l  = s * fmaf(sv, ratio, 1.0f);
            acc[t][i] = l;
            mx = fmaxf(mx, l);
        }
    mx = fmaxf(mx, __shfl_xor(mx, 16, 64));
    mx = fmaxf(mx, __shfl_xor(mx, 32, 64));
    if (quad == 0) sred[2][wv][l16] = mx;
    __syncthreads();
    const float mrow = fmaxf(fmaxf(sred[2][0][l16], sred[2][1][l16]),
                             fmaxf(sred[2][2][l16], sred[2][3][l16]));

    // phase 3: exp + sum
    float rs = 0.f;
#pragma unroll
    for (int t = 0; t < 16; t++)
#pragma unroll
        for (int i = 0; i < 4; i++) {
            float p = __expf(acc[t][i] - mrow);
            acc[t][i] = p;
            rs += p;
        }
    rs += __shfl_xor(rs, 16, 64); rs += __shfl_xor(rs, 32, 64);
    if (quad == 0) sred[3][wv][l16] = rs;
    __syncthreads();
    const float hsum = hm[0] + hm[1] + hm[2] + hm[3] + hm[4] + hm[5] + hm[6] + hm[7];
    const float hscale = hm[h] * 8.0f / hsum;
    const float rsum = sred[3][0][l16] + sred[3][1][l16] + sred[3][2][l16] + sred[3][3][l16];
    const float rinv = hscale / rsum;

    // pack P to bf16 (frees acc)
    s16x4 pk[16];
#pragma unroll
    for (int t = 0; t < 16; t++)
        pk[t] = (s16x4){ f2bf(acc[t][0] * rinv), f2bf(acc[t][1] * rinv),
                         f2bf(acc[t][2] * rinv), f2bf(acc[t][3] * rinv) };

    // split PV: half 0 = keys [0,512) (waves 0,1), half 1 = keys [512,1024)
    const short* vb = vt + ((size_t)bh * 64 + wv * 16 + l16) * 1024;
    const int c0 = (wv & 1) * 256 + quad * 4;
    f32x4 oacc = (f32x4){0.f, 0.f, 0.f, 0.f};

    if (wv < 2) {
#pragma unroll
        for (int t = 0; t < 16; t++)
            *(s16x4*)&sP[l16][c0 + t * 16] = pk[t];
    }
    __syncthreads();
#pragma unroll
    for (int kk2 = 0; kk2 < 16; kk2++) {
        short8 pa = *(const short8*)&sP[l16][kk2 * 32 + quad * 8];
        short8 vf = *(const short8*)(vb + kk2 * 32 + quad * 8);
        oacc = __builtin_amdgcn_mfma_f32_16x16x32_bf16(pa, vf, oacc, 0, 0, 0);
    }
    __syncthreads();
    if (wv >= 2) {
#pragma unroll
        for (int t = 0; t < 16; t++)
            *(s16x4*)&sP[l16][c0 + t * 16] = pk[t];
    }
    __syncthreads();
#pragma unroll
    for (int kk2 = 0; kk2 < 16; kk2++) {
        short8 pa = *(const short8*)&sP[l16][kk2 * 32 + quad * 8];
        short8 vf = *(const short8*)(vb + 512 + kk2 * 32 + quad * 8);
        oacc = __builtin_amdgcn_mfma_f32_16x16x32_bf16(pa, vf, oacc, 0, 0, 0);
    }

#pragma unroll
    for (int i = 0; i < 4; i++)
        o[((size_t)(b * 1024 + q0 + quad * 4 + i)) * 512 + h * 64 + wv * 16 + l16]
            = f2bf(oacc[i]);
}

// ---------------------------------------------------------------------------
// K3: out = O @ WoT^T + b_out  (M=8192, K=512, N=512), 128x128 tile, fp32 out
// ---------------------------------------------------------------------------
__global__ __launch_bounds__(256) void out_gemm(
    const short* __restrict__ A, const short* __restrict__ BT,
    const float* __restrict__ bias, float* __restrict__ out)
{
    __shared__ short sA[128][32];
    __shared__ short sB[128][32];

    const int tid  = threadIdx.x;
    const int wv   = tid >> 6, lane = tid & 63;
    const int quad = lane >> 4, l16 = lane & 15;
    const int wr = wv >> 1, wc = wv & 1;
    const int m0 = blockIdx.x * 128, n0 = blockIdx.y * 128;

    f32x4 acc[4][4];
#pragma unroll
    for (int i = 0; i < 4; i++)
#pragma unroll
        for (int j = 0; j < 4; j++) acc[i][j] = (f32x4){0.f, 0.f, 0.f, 0.f};

    const short* a_src = A  + (size_t)(m0 + wv * 32 + (lane >> 2)) * 512 + (lane & 3) * 8;
    const short* b_src = BT + (size_t)(n0 + wv * 32 + (lane >> 2)) * 512 + (lane & 3) * 8;
    char* a_dst = (char*)sA + wv * 2048;
    char* b_dst = (char*)sB + wv * 2048;

    for (int ks = 0; ks < 16; ks++) {
        __syncthreads();
        const short* ap = a_src + ks * 32;
        const short* bp = b_src + ks * 32;
        __builtin_amdgcn_global_load_lds((gp1)(ap),            (lp3)(a_dst),        16, 0, 0);
        __builtin_amdgcn_global_load_lds((gp1)(ap + 16 * 512), (lp3)(a_dst + 1024), 16, 0, 0);
        __builtin_amdgcn_global_load_lds((gp1)(bp),            (lp3)(b_dst),        16, 0, 0);
        __builtin_amdgcn_global_load_lds((gp1)(bp + 16 * 512), (lp3)(b_dst + 1024), 16, 0, 0);
        __syncthreads();

        short8 af[4], bf[4];
#pragma unroll
        for (int f = 0; f < 4; f++) {
            af[f] = *(const short8*)&sA[wr * 64 + f * 16 + l16][quad * 8];
            bf[f] = *(const short8*)&sB[wc * 64 + f * 16 + l16][quad * 8];
        }
#pragma unroll
        for (int fm = 0; fm < 4; fm++)
#pragma unroll
            for (int fn = 0; fn < 4; fn++)
                acc[fm][fn] = __builtin_amdgcn_mfma_f32_16x16x32_bf16(
                    af[fm], bf[fn], acc[fm][fn], 0, 0, 0);
    }

#pragma unroll
    for (int fn = 0; fn < 4; fn++) {
        const int gc = n0 + wc * 64 + fn * 16 + l16;
        const float bv = bias[gc];
#pragma unroll
        for (int fm = 0; fm < 4; fm++)
#pragma unroll
            for (int i = 0; i < 4; i++) {
                const int gm = m0 + wr * 64 + fm * 16 + quad * 4 + i;
                out[(size_t)gm * 512 + gc] = acc[fm][fn][i] + bv;
            }
    }
}

// ---------------------------------------------------------------------------
extern "C" void kernel_launch(void* const* d_in, const int* in_sizes, int n_in,
                              void* d_out, int out_size, void* d_ws, size_t ws_size,
                              hipStream_t stream) {
    const float* x    = (const float*)d_in[0];
    const float* spd  = (const float*)d_in[1];
    const float* hm   = (const float*)d_in[2];
    const float* Wqkv = (const float*)d_in[3];
    const float* Wout = (const float*)d_in[4];
    const float* bout = (const float*)d_in[5];
    float* out = (float*)d_out;

    char* ws = (char*)d_ws;
    short* qw  = (short*)(ws);                      // 8 MB  [bh][n][d] bf16 (pre-scaled)
    short* kw  = (short*)(ws + ((size_t)8  << 20)); // 8 MB  [bh][n][d] bf16
    short* vtw = (short*)(ws + ((size_t)16 << 20)); // 8 MB  [bh][d][n] bf16
    short* ow  = (short*)(ws + ((size_t)24 << 20)); // 8 MB  [b][n][h*64+d] bf16
    short* xb  = (short*)(ws + ((size_t)32 << 20)); // 8 MB  x bf16 [8192][512]
    short* wqT = (short*)(ws + ((size_t)40 << 20)); // 1.5MB Wqkv^T bf16 [1536][512]
    short* woT = (short*)(ws + ((size_t)42 << 20)); // 0.5MB Wout^T bf16 [512][512]

    cvt_bf16<<<4096, 256, 0, stream>>>(x, xb, 8192 * 512 / 4);
    tr_w    <<<dim3(8, 24), 256, 0, stream>>>(Wqkv, wqT, 512, 1536);
    tr_w    <<<dim3(8, 8),  256, 0, stream>>>(Wout, woT, 512, 512);

    qkv_gemm<<<dim3(64, 12), 256, 0, stream>>>(xb, wqT, qw, kw, vtw);
    attn_k  <<<dim3(64, 64), 256, 0, stream>>>(qw, kw, vtw, spd, hm, ow);
    out_gemm<<<dim3(64, 4),  256, 0, stream>>>(ow, woT, bout, out);
}